// Round 4
// baseline (971.090 us; speedup 1.0000x reference)
//
#include <hip/hip_runtime.h>
#include <math.h>

// B=64, G=2048, S=64, C=3 -> 131072 groups of 64 samples.
// Bit-faithful emulation of the numpy-f32 pipeline (LAPACK ssyevd, modern
// >=3.10 slartg), strict IEEE per-op (no FMA contraction anywhere).
static constexpr int kS = 64;

__device__ __forceinline__ float slapy2_(float x, float y) {
    _Pragma("clang fp contract(off)")
    float xa = fabsf(x), ya = fabsf(y);
    float w = fmaxf(xa, ya), z = fminf(xa, ya);
    if (z == 0.0f) return w;
    float t = z / w;
    return w * sqrtf(1.0f + t * t);
}

// LAPACK >= 3.10 slartg (fast path; our magnitudes are mid-range).
__device__ __forceinline__ void slartg_(float f, float g,
                                        float &c, float &s, float &r) {
    _Pragma("clang fp contract(off)")
    if (g == 0.0f) { c = 1.0f; s = 0.0f; r = f; return; }
    if (f == 0.0f) { c = 0.0f; s = (g >= 0.0f) ? 1.0f : -1.0f; r = fabsf(g); return; }
    float d = sqrtf(f * f + g * g);
    float p = 1.0f / d;
    c = fabsf(f) * p;
    s = g * ((f >= 0.0f) ? p : -p);
    r = (f >= 0.0f) ? d : -d;
}

__device__ __forceinline__ void slaev2_(float a, float b, float cc,
                                        float &rt1, float &rt2,
                                        float &cs1, float &sn1) {
    _Pragma("clang fp contract(off)")
    float sm = a + cc, df = a - cc;
    float adf = fabsf(df);
    float tb = b + b;
    float ab = fabsf(tb);
    float acmx, acmn;
    if (fabsf(a) > fabsf(cc)) { acmx = a; acmn = cc; } else { acmx = cc; acmn = a; }
    float rt;
    if (adf > ab)      { float t = ab / adf; rt = adf * sqrtf(1.0f + t * t); }
    else if (adf < ab) { float t = adf / ab; rt = ab * sqrtf(1.0f + t * t); }
    else                rt = ab * sqrtf(2.0f);
    int sgn1;
    if (sm < 0.0f)      { rt1 = 0.5f * (sm - rt); sgn1 = -1; rt2 = (acmx / rt1) * acmn - (b / rt1) * b; }
    else if (sm > 0.0f) { rt1 = 0.5f * (sm + rt); sgn1 =  1; rt2 = (acmx / rt1) * acmn - (b / rt1) * b; }
    else                { rt1 = 0.5f * rt; rt2 = -0.5f * rt; sgn1 = 1; }
    int sgn2;
    float cs;
    if (df >= 0.0f) { cs = df + rt; sgn2 = 1; } else { cs = df - rt; sgn2 = -1; }
    float acs = fabsf(cs);
    if (acs > ab) {
        float ct = -tb / cs;
        sn1 = 1.0f / sqrtf(1.0f + ct * ct);
        cs1 = ct * sn1;
    } else {
        if (ab == 0.0f) { cs1 = 1.0f; sn1 = 0.0f; }
        else {
            float tn = -cs / tb;
            cs1 = 1.0f / sqrtf(1.0f + tn * tn);
            sn1 = tn * cs1;
        }
    }
    if (sgn1 == sgn2) { float tn = cs1; cs1 = -sn1; sn1 = tn; }
}

// slasr single rotation (columns j, j+1, 1-based), exact reference formula.
__device__ __forceinline__ void zrot_(float z[4][4], int j, float ctemp, float stemp) {
    _Pragma("clang fp contract(off)")
    for (int i = 1; i <= 3; ++i) {
        float temp = z[i][j + 1];
        z[i][j + 1] = (ctemp * temp) - (stemp * z[i][j]);
        z[i][j]     = (stemp * temp) + (ctemp * z[i][j]);
    }
}

// ssteqr('I') for n=3, faithful LAPACK control flow (1-based arrays).
__device__ void ssteqr3_(float *d, float *e, float z[4][4]) {
    _Pragma("clang fp contract(off)")
    const float EPS    = 5.9604644775390625e-8f;   // slamch('E') = 2^-24
    const float EPS2   = EPS * EPS;
    const float SAFMIN = 1.17549435e-38f;
    const int n = 3, nmaxit = 3 * 30;
    int jtot = 0, l1 = 1;

    while (true) {                       // label 10
        if (l1 > n) break;
        if (l1 > 1) e[l1 - 1] = 0.0f;
        int m = n;
        for (int mm = l1; mm <= n - 1; ++mm) {
            float tst = fabsf(e[mm]);
            if (tst == 0.0f) { m = mm; break; }
            if (tst <= (sqrtf(fabsf(d[mm])) * sqrtf(fabsf(d[mm + 1]))) * EPS) {
                e[mm] = 0.0f; m = mm; break;
            }
        }
        int l = l1, lsv = l, lend = m, lendsv = lend;
        l1 = m + 1;
        if (lend == l) continue;
        // slascl scaling skipped: block norms ~1e2..1e4, inside [ssfmin, ssfmax]
        if (fabsf(d[lend]) < fabsf(d[l])) { lend = lsv; l = lendsv; }

        if (lend > l) {
            // ---- QL ----
            while (true) {               // label 40
                m = lend;
                if (l != lend) {
                    for (int mm = l; mm <= lend - 1; ++mm) {
                        float tst = e[mm] * e[mm];
                        if (tst <= (EPS2 * fabsf(d[mm])) * fabsf(d[mm + 1]) + SAFMIN) { m = mm; break; }
                    }
                }
                if (m < lend) e[m] = 0.0f;
                float p = d[l];
                if (m == l) {            // label 80
                    d[l] = p; ++l;
                    if (l <= lend) continue;
                    break;
                }
                if (m == l + 1) {
                    float rt1, rt2, c, s;
                    slaev2_(d[l], e[l], d[l + 1], rt1, rt2, c, s);
                    zrot_(z, l, c, s);
                    d[l] = rt1; d[l + 1] = rt2; e[l] = 0.0f; l += 2;
                    if (l <= lend) continue;
                    break;
                }
                if (jtot == nmaxit) break;
                ++jtot;
                float g = (d[l + 1] - p) / (2.0f * e[l]);
                float r = slapy2_(g, 1.0f);
                g = d[m] - p + e[l] / (g + ((g >= 0.0f) ? r : -r));  // sign(r,g)
                float s = 1.0f, c = 1.0f;
                p = 0.0f;
                for (int i = m - 1; i >= l; --i) {
                    float f = s * e[i];
                    float b = c * e[i];
                    slartg_(g, f, c, s, r);
                    if (i != m - 1) e[i + 1] = r;
                    g = d[i + 1] - p;
                    float r2 = ((d[i] - g) * s) + ((2.0f * c) * b);
                    p = s * r2;
                    d[i + 1] = g + p;
                    g = (c * r2) - b;
                    zrot_(z, i, c, -s);  // QL stores -s
                }
                d[l] = d[l] - p;
                e[l] = g;
            }
        } else if (lend < l) {
            // ---- QR ----
            while (true) {               // label 90
                m = lend;
                if (l != lend) {
                    for (int mm = l; mm >= lend + 1; --mm) {
                        float tst = e[mm - 1] * e[mm - 1];
                        if (tst <= (EPS2 * fabsf(d[mm])) * fabsf(d[mm - 1]) + SAFMIN) { m = mm; break; }
                    }
                }
                if (m > lend) e[m - 1] = 0.0f;
                float p = d[l];
                if (m == l) {            // label 130
                    d[l] = p; --l;
                    if (l >= lend) continue;
                    break;
                }
                if (m == l - 1) {
                    float rt1, rt2, c, s;
                    slaev2_(d[l - 1], e[l - 1], d[l], rt1, rt2, c, s);
                    zrot_(z, l - 1, c, s);
                    d[l - 1] = rt1; d[l] = rt2; e[l - 1] = 0.0f; l -= 2;
                    if (l >= lend) continue;
                    break;
                }
                if (jtot == nmaxit) break;
                ++jtot;
                float g = (d[l - 1] - p) / (2.0f * e[l - 1]);
                float r = slapy2_(g, 1.0f);
                g = d[m] - p + e[l - 1] / (g + ((g >= 0.0f) ? r : -r));
                float s = 1.0f, c = 1.0f;
                p = 0.0f;
                for (int i = m; i <= l - 1; ++i) {
                    float f = s * e[i];
                    float b = c * e[i];
                    slartg_(g, f, c, s, r);
                    if (i != m) e[i - 1] = r;
                    g = d[i] - p;
                    float r2 = ((d[i + 1] - g) * s) + ((2.0f * c) * b);
                    p = s * r2;
                    d[i] = g + p;
                    g = (c * r2) - b;
                    zrot_(z, i, c, s);   // QR stores +s
                }
                d[l] = d[l] - p;
                e[l - 1] = g;
            }
        }
    }
    // label 160: selection sort ascending, swap eigenvector columns.
    for (int ii = 2; ii <= n; ++ii) {
        int i = ii - 1, k = i;
        float p = d[i];
        for (int j = ii; j <= n; ++j) {
            if (d[j] < p) { k = j; p = d[j]; }
        }
        if (k != i) {
            d[k] = d[i]; d[i] = p;
            for (int r = 1; r <= 3; ++r) { float t = z[r][i]; z[r][i] = z[r][k]; z[r][k] = t; }
        }
    }
}

__global__ __launch_bounds__(256) void lrf_kernel(const float* __restrict__ nbr,
                                                  float* __restrict__ rot,
                                                  float* __restrict__ lrf) {
    _Pragma("clang fp contract(off)")
    const int lane = threadIdx.x & 63;
    const long long gid = ((long long)blockIdx.x << 2) + (threadIdx.x >> 6);
    const long long base = gid * (kS * 3) + (long long)lane * 3;

    const float px = nbr[base + 0];
    const float py = nbr[base + 1];
    const float pz = nbr[base + 2];

    // norm: np order ((x*x + y*y) + z*z), each product rounded, no FMA
    float t_ = (px * px) + (py * py);
    t_ = t_ + (pz * pz);
    const float nrm = sqrtf(t_);

    // max over 64 (exact, order-free)
    float mx = nrm;
#pragma unroll
    for (int m = 1; m < 64; m <<= 1) mx = fmaxf(mx, __shfl_xor(mx, m, 64));
    const float w = mx - nrm;

    // np.sum pairwise order for n=64: r_j = w_j + w_{j+8} + ... + w_{j+56}
    // (sequential), then ((r0+r1)+(r2+r3)) + ((r4+r5)+(r6+r7)).
    const int j8 = lane & 7;
    float r_ = __shfl(w, j8, 64);
#pragma unroll
    for (int k = 1; k < 8; ++k) r_ = r_ + __shfl(w, j8 + 8 * k, 64);
    const float q0 = __shfl(r_, 0, 64), q1 = __shfl(r_, 1, 64);
    const float q2 = __shfl(r_, 2, 64), q3 = __shfl(r_, 3, 64);
    const float q4 = __shfl(r_, 4, 64), q5 = __shfl(r_, 5, 64);
    const float q6 = __shfl(r_, 6, 64), q7 = __shfl(r_, 7, 64);
    const float ws = ((q0 + q1) + (q2 + q3)) + ((q4 + q5) + (q6 + q7));
    const float denom = ws + 1e-6f;
    const float wq = w / denom;

    // scaled_pos and A = w * scaled_pos (elementwise, each rounded)
    const float spx = 100.0f * px, spy = 100.0f * py, spz = 100.0f * pz;
    const float ax = wq * spx, ay = wq * spy, az = wq * spz;

    // einsum: sequential ascending s, per-product rounding. eigh uses the
    // LOWER triangle: C[k,l] = sum_s A[s,k]*B[s,l] with k >= l.
    float c00 = 0.0f, c10 = 0.0f, c20 = 0.0f, c11 = 0.0f, c21 = 0.0f, c22 = 0.0f;
    for (int s = 0; s < 64; ++s) {
        const float bx = __shfl(spx, s, 64);
        const float by = __shfl(spy, s, 64);
        const float bz = __shfl(spz, s, 64);
        const float Ax = __shfl(ax, s, 64);
        const float Ay = __shfl(ay, s, 64);
        const float Az = __shfl(az, s, 64);
        c00 = c00 + (Ax * bx);
        c10 = c10 + (Ay * bx);
        c20 = c20 + (Az * bx);
        c11 = c11 + (Ay * by);
        c21 = c21 + (Az * by);
        c22 = c22 + (Az * bz);
    }

    const float a11 = c00, a21 = c10, a31 = c20, a22 = c11, a32 = c21, a33 = c22;

    // --- ssytd2 (UPLO='L', n=3), exact reference-BLAS op order ---
    float taui, v2, e1, d2, d3, e2;
    const float xnorm = fabsf(a31);   // snrm2(1,x)
    if (xnorm == 0.0f) {
        taui = 0.0f; v2 = a31; e1 = a21; d2 = a22; e2 = a32; d3 = a33;
    } else {
        const float beta = -copysignf(slapy2_(a21, xnorm), a21);
        taui = (beta - a21) / beta;
        const float rcp = 1.0f / (a21 - beta);   // sscal multiplies by reciprocal
        v2 = a31 * rcp;
        e1 = beta;
        // ssymv (reference order), alpha=taui, x=(1,v2), y:=0:
        float x1 = taui * a22;                 // y1 = temp1*A(1,1), temp1 = taui
        float x2 = taui * a32;                 // y2 = temp1*A(2,1)
        const float temp2 = a32 * v2;          // dot accumulation col 1
        x1 = x1 + (taui * temp2);              // y1 += alpha*temp2
        const float t1v = taui * v2;           // j=2: temp1 = alpha*x(2)
        x2 = x2 + (t1v * a33);                 // y2 += temp1*A(2,2)
        // sdot: x1*1 + x2*v2 sequential
        const float dt = x1 + (x2 * v2);
        const float alpha_c = (-0.5f * taui) * dt;
        // saxpy: w = x + alpha_c*v
        const float w1 = x1 + alpha_c;
        const float w2 = x2 + (alpha_c * v2);
        // ssyr2 alpha=-1 (reference order): A += x*temp1 + y*temp2 per column
        d2 = (a22 - w1) - w1;
        e2 = (a32 - (v2 * w1)) - w2;
        d3 = (a33 - (v2 * w2)) - (w2 * v2);
    }

    float d_[4] = {0.0f, a11, d2, d3};
    float e_[3] = {0.0f, e1, e2};
    float z[4][4];
#pragma unroll
    for (int i = 1; i <= 3; ++i)
#pragma unroll
        for (int j = 1; j <= 3; ++j) z[i][j] = (i == j) ? 1.0f : 0.0f;

    ssteqr3_(d_, e_, z);

    // --- sormtr/sorm2r/slarf: apply H = I - tau*v*v' to columns 1 and 3 ---
    float zv0, zv1, zv2, xv0, xv1, xv2;
    {
        float u2 = z[2][1], u3 = z[3][1];
        zv0 = z[1][1];
        if (taui != 0.0f) {
            const float wj = u2 + (u3 * v2);   // sgemv 'T'
            const float pj = taui * wj;        // sger: temp = -tau*wj (negation exact)
            zv1 = u2 - pj;
            zv2 = u3 - (v2 * pj);
        } else { zv1 = u2; zv2 = u3; }
    }
    {
        float u2 = z[2][3], u3 = z[3][3];
        xv0 = z[1][3];
        if (taui != 0.0f) {
            const float wj = u2 + (u3 * v2);
            const float pj = taui * wj;
            xv1 = u2 - pj;
            xv2 = u3 - (v2 * pj);
        } else { xv1 = u2; xv2 = u3; }
    }

    // --- sign disambiguation: proj = (v0*p0 + v1*p1) + v2*p2; flip iff n_pos<32 ---
    const float projz = ((zv0 * px) + (zv1 * py)) + (zv2 * pz);
    if (__popcll(__ballot(projz > 0.0f)) < 32) { zv0 = -zv0; zv1 = -zv1; zv2 = -zv2; }
    const float projx = ((xv0 * px) + (xv1 * py)) + (xv2 * pz);
    if (__popcll(__ballot(projx > 0.0f)) < 32) { xv0 = -xv0; xv1 = -xv1; xv2 = -xv2; }

    // y = cross(z, x), per-op rounding
    const float yv0 = (zv1 * xv2) - (zv2 * xv1);
    const float yv1 = (zv2 * xv0) - (zv0 * xv2);
    const float yv2 = (zv0 * xv1) - (zv1 * xv0);

    // rot[s,d] = (p0*L[0,d] + p1*L[1,d]) + p2*L[2,d], columns (z,y,x)
    rot[base + 0] = ((px * zv0) + (py * zv1)) + (pz * zv2);
    rot[base + 1] = ((px * yv0) + (py * yv1)) + (pz * yv2);
    rot[base + 2] = ((px * xv0) + (py * xv1)) + (pz * xv2);

    // lrfs[c][d]: c = component, d selects (z,y,x)
    if (lane < 9) {
        const int c = lane / 3;
        const int dcol = lane - c * 3;
        const float zc = (c == 0) ? zv0 : ((c == 1) ? zv1 : zv2);
        const float yc = (c == 0) ? yv0 : ((c == 1) ? yv1 : yv2);
        const float xc = (c == 0) ? xv0 : ((c == 1) ? xv1 : xv2);
        lrf[gid * 9 + lane] = (dcol == 0) ? zc : ((dcol == 1) ? yc : xc);
    }
}

extern "C" void kernel_launch(void* const* d_in, const int* in_sizes, int n_in,
                              void* d_out, int out_size, void* d_ws, size_t ws_size,
                              hipStream_t stream) {
    const float* neighbor = (const float*)d_in[0];
    // d_in[1] (center) is unused by the reference computation.
    float* rot = (float*)d_out;                                  // (B,G,S,3)
    float* lrf = (float*)d_out + (long long)64 * 2048 * 64 * 3;  // (B,G,3,3)

    lrf_kernel<<<dim3(32768), dim3(256), 0, stream>>>(neighbor, rot, lrf);
}